// Round 1
// baseline (1028.122 us; speedup 1.0000x reference)
//
#include <hip/hip_runtime.h>

#define NROWS 65536   // B*T
#define DIM   256
#define VCB   2048

// ---------------- ws layout (bytes) ----------------
// [0,        262144)  idx        int[NROWS]
// [262144,   270336)  hist       uint[VCB]
// [270336,   272384)  loss_part  double[256]
// [272384,   280576)  enorm      float[VCB]

// prep: zero hist + loss partials, compute ||e_j||^2 (one wave per codebook row)
__global__ __launch_bounds__(256) void prep_kernel(
    const float* __restrict__ e, float* __restrict__ enorm,
    unsigned int* __restrict__ hist, double* __restrict__ loss_part) {
  int tid = threadIdx.x;
  int gt = blockIdx.x * 256 + tid;
  if (gt < VCB) hist[gt] = 0u;
  if (gt < 256) loss_part[gt] = 0.0;

  int wid  = gt >> 6;        // global wave id = codebook row
  int lane = tid & 63;
  if (wid < VCB) {
    const float4* row = (const float4*)(e + (size_t)wid * DIM);
    float4 v = row[lane];                       // 64 lanes * 4 = 256 elems
    float s = v.x*v.x + v.y*v.y + v.z*v.z + v.w*v.w;
    #pragma unroll
    for (int off = 32; off; off >>= 1) s += __shfl_xor(s, off);
    if (lane == 0) enorm[wid] = s;
  }
}

// fused distance GEMM + row argmin.
// block = 256 threads, tile BM=64 rows x BN=64 codes, BK=16.
// thread (tr,tc) tr=tid>>4, tc=tid&15 owns rows tr*4..+3, cols tc*4..+3.
__global__ __launch_bounds__(256) void argmin_kernel(
    const float* __restrict__ z, const float* __restrict__ e,
    const float* __restrict__ enorm, int* __restrict__ idx_out,
    float* __restrict__ idxf_out, unsigned int* __restrict__ hist) {
  __shared__ float zs[16][68];   // [k][row], stride 68 keeps 16B alignment, spreads banks
  __shared__ float es[16][68];   // [k][col]

  const int tid = threadIdx.x;
  const int tr = tid >> 4;       // 0..15 row group
  const int tc = tid & 15;       // 0..15 col group
  const int rowbase = blockIdx.x * 64;

  float minv[4];
  int   mini[4];
  #pragma unroll
  for (int ii = 0; ii < 4; ++ii) { minv[ii] = 3.4e38f; mini[ii] = 0; }

  const int r  = tid >> 2;             // staging: row/col 0..63
  const int kq = (tid & 3) << 2;       // staging: k offset 0,4,8,12

  for (int vt = 0; vt < VCB; vt += 64) {
    float acc[4][4] = {};
    for (int kt = 0; kt < DIM; kt += 16) {
      // issue global loads early
      const float4 zv = *(const float4*)(z + (size_t)(rowbase + r) * DIM + kt + kq);
      const float4 ev = *(const float4*)(e + (size_t)(vt      + r) * DIM + kt + kq);
      __syncthreads();   // previous iteration's LDS reads done
      zs[kq+0][r] = zv.x; zs[kq+1][r] = zv.y; zs[kq+2][r] = zv.z; zs[kq+3][r] = zv.w;
      es[kq+0][r] = ev.x; es[kq+1][r] = ev.y; es[kq+2][r] = ev.z; es[kq+3][r] = ev.w;
      __syncthreads();
      #pragma unroll
      for (int k = 0; k < 16; ++k) {
        float4 a = *(const float4*)&zs[k][tr << 2];
        float4 b = *(const float4*)&es[k][tc << 2];
        float ar[4] = {a.x, a.y, a.z, a.w};
        float br[4] = {b.x, b.y, b.z, b.w};
        #pragma unroll
        for (int ii = 0; ii < 4; ++ii)
          #pragma unroll
          for (int jj = 0; jj < 4; ++jj)
            acc[ii][jj] = fmaf(ar[ii], br[jj], acc[ii][jj]);
      }
      __syncthreads();
    }
    // epilogue: s_j = ||e_j||^2 - 2 * dot  (||z||^2 is row-constant, argmin-invariant)
    #pragma unroll
    for (int jj = 0; jj < 4; ++jj) {
      int j = vt + (tc << 2) + jj;
      float en = enorm[j];
      #pragma unroll
      for (int ii = 0; ii < 4; ++ii) {
        float s = fmaf(-2.f, acc[ii][jj], en);
        if (s < minv[ii]) { minv[ii] = s; mini[ii] = j; }   // strict <: keeps first idx
      }
    }
  }

  // reduce across the 16 lanes (tc) sharing each row; first-index tie-break
  #pragma unroll
  for (int off = 8; off; off >>= 1) {
    #pragma unroll
    for (int ii = 0; ii < 4; ++ii) {
      float ov = __shfl_xor(minv[ii], off);
      int   oi = __shfl_xor(mini[ii], off);
      if (ov < minv[ii] || (ov == minv[ii] && oi < mini[ii])) {
        minv[ii] = ov; mini[ii] = oi;
      }
    }
  }
  if (tc == 0) {
    #pragma unroll
    for (int ii = 0; ii < 4; ++ii) {
      int n = rowbase + (tr << 2) + ii;
      int bi = mini[ii];
      idx_out[n]  = bi;
      idxf_out[n] = (float)bi;
      atomicAdd(&hist[bi], 1u);
    }
  }
}

// gather z_q = e[idx], write z_q_st, accumulate sum((z - z_q)^2)
__global__ __launch_bounds__(256) void gather_loss_kernel(
    const float* __restrict__ z, const float* __restrict__ e,
    const int* __restrict__ idx, float* __restrict__ zq_out,
    double* __restrict__ loss_part) {
  __shared__ float wsum[4];
  int tid  = threadIdx.x;
  int w    = tid >> 6;
  int lane = tid & 63;
  int n    = blockIdx.x * 4 + w;

  int ci = idx[n];
  const float4* zr = (const float4*)(z + (size_t)n  * DIM);
  const float4* er = (const float4*)(e + (size_t)ci * DIM);
  float4 zv = zr[lane];
  float4 ev = er[lane];
  ((float4*)(zq_out + (size_t)n * DIM))[lane] = ev;

  float dx = zv.x - ev.x, dy = zv.y - ev.y, dz = zv.z - ev.z, dw = zv.w - ev.w;
  float s = dx*dx + dy*dy + dz*dz + dw*dw;
  #pragma unroll
  for (int off = 32; off; off >>= 1) s += __shfl_xor(s, off);
  if (lane == 0) wsum[w] = s;
  __syncthreads();
  if (tid == 0) {
    float bs = wsum[0] + wsum[1] + wsum[2] + wsum[3];
    atomicAdd(&loss_part[blockIdx.x & 255], (double)bs);
  }
}

__global__ __launch_bounds__(256) void finalize_kernel(
    const unsigned int* __restrict__ hist, const double* __restrict__ loss_part,
    float* __restrict__ out) {
  __shared__ double lsh[4];
  __shared__ float  hsh[4];
  __shared__ float  denom_sh;
  int tid = threadIdx.x, lane = tid & 63, w = tid >> 6;

  float hs = 0.f;
  for (int j = tid; j < VCB; j += 256) hs += (float)hist[j];
  double ls = loss_part[tid];
  #pragma unroll
  for (int off = 32; off; off >>= 1) {
    hs += __shfl_xor(hs, off);
    ls += __shfl_xor(ls, off);
  }
  if (lane == 0) { lsh[w] = ls; hsh[w] = hs; }
  __syncthreads();
  if (tid == 0) {
    double lt = lsh[0] + lsh[1] + lsh[2] + lsh[3];
    float  ht = hsh[0] + hsh[1] + hsh[2] + hsh[3];
    out[0] = (float)(lt / (double)((size_t)NROWS * DIM));
    denom_sh = ht + 1e-8f;
  }
  __syncthreads();
  float denom = denom_sh;
  float* prob = out + 1 + (size_t)NROWS * DIM + NROWS;
  for (int j = tid; j < VCB; j += 256) prob[j] = (float)hist[j] / denom;
}

extern "C" void kernel_launch(void* const* d_in, const int* in_sizes, int n_in,
                              void* d_out, int out_size, void* d_ws, size_t ws_size,
                              hipStream_t stream) {
  (void)in_sizes; (void)n_in; (void)out_size; (void)ws_size;
  const float* z = (const float*)d_in[0];
  const float* e = (const float*)d_in[1];
  float* out = (float*)d_out;
  char*  ws  = (char*)d_ws;

  int*          idx       = (int*)ws;
  unsigned int* hist      = (unsigned int*)(ws + 262144);
  double*       loss_part = (double*)(ws + 270336);
  float*        enorm     = (float*)(ws + 272384);

  float* out_zq  = out + 1;
  float* out_idx = out + 1 + (size_t)NROWS * DIM;

  prep_kernel<<<512, 256, 0, stream>>>(e, enorm, hist, loss_part);
  argmin_kernel<<<NROWS / 64, 256, 0, stream>>>(z, e, enorm, idx, out_idx, hist);
  gather_loss_kernel<<<NROWS / 4, 256, 0, stream>>>(z, e, idx, out_zq, loss_part);
  finalize_kernel<<<1, 256, 0, stream>>>(hist, loss_part, out);
}

// Round 3
// 422.044 us; speedup vs baseline: 2.4361x; 2.4361x over previous
//
#include <hip/hip_runtime.h>

#define NROWS 65536   // B*T
#define DIM   256
#define VCB   2048

typedef _Float16 f16;
typedef _Float16 f16x8 __attribute__((ext_vector_type(8)));
typedef float    f32x4 __attribute__((ext_vector_type(4)));

// ---------------- ws layout (bytes) ----------------
// [0,        262144)  idx        int[NROWS]
// [262144,   270336)  hist       uint[VCB]
// [270336,   272384)  loss_part  double[256]
// [272384,   280576)  enorm      float[VCB]
// [524288,  1572864)  e_hi       f16[VCB*DIM]
// [1572864, 2621440)  e_lo       f16[VCB*DIM]
// z_hi/z_lo (64 MB) live in d_out's z_q region as scratch until the gather pass.

__device__ __forceinline__ void async16(void* lds, const void* g) {
  __builtin_amdgcn_global_load_lds(
      (const __attribute__((address_space(1))) void*)g,
      (__attribute__((address_space(3))) void*)lds, 16, 0, 0);
}

// fp32 -> (f16 hi, f16 lo) split, 4 elems/thread/iter, grid-stride
__global__ __launch_bounds__(256) void convert_kernel(
    const float4* __restrict__ src, short4* __restrict__ dhi,
    short4* __restrict__ dlo, int n4) {
  int stride = gridDim.x * 256;
  for (int i = blockIdx.x * 256 + threadIdx.x; i < n4; i += stride) {
    float4 v = src[i];
    union { f16 h[4]; short4 s; } H, L;
    H.h[0] = (f16)v.x; H.h[1] = (f16)v.y; H.h[2] = (f16)v.z; H.h[3] = (f16)v.w;
    L.h[0] = (f16)(v.x - (float)H.h[0]);
    L.h[1] = (f16)(v.y - (float)H.h[1]);
    L.h[2] = (f16)(v.z - (float)H.h[2]);
    L.h[3] = (f16)(v.w - (float)H.h[3]);
    dhi[i] = H.s; dlo[i] = L.s;
  }
}

// zero hist + loss partials, compute ||e_j||^2 (one wave per codebook row), fp32
__global__ __launch_bounds__(256) void prep_kernel(
    const float* __restrict__ e, float* __restrict__ enorm,
    unsigned int* __restrict__ hist, double* __restrict__ loss_part) {
  int tid = threadIdx.x;
  int gt = blockIdx.x * 256 + tid;
  if (gt < VCB) hist[gt] = 0u;
  if (gt < 256) loss_part[gt] = 0.0;
  int wid  = gt >> 6;
  int lane = tid & 63;
  if (wid < VCB) {
    const float4* row = (const float4*)(e + (size_t)wid * DIM);
    float4 v = row[lane];
    float s = v.x*v.x + v.y*v.y + v.z*v.z + v.w*v.w;
    #pragma unroll
    for (int off = 32; off; off >>= 1) s += __shfl_xor(s, off);
    if (lane == 0) enorm[wid] = s;
  }
}

// Fused split-f16 MFMA distance GEMM + row argmin.
// 256 threads = 4 waves (2x2), tile 128 rows x 128 cols per vt step,
// each wave owns 64x64 = 4x4 frags of mfma_f32_16x16x32_f16. BK=32.
// s_j = ||e_j||^2 - 2*dot (||z||^2 row-constant, argmin-invariant).
// Cross-wave (wc=0 vs wc=1) argmin merged through LDS at the end.
__global__ __launch_bounds__(256) void argmin_kernel(
    const f16* __restrict__ zh, const f16* __restrict__ zl,
    const f16* __restrict__ eh, const f16* __restrict__ el,
    const float* __restrict__ enorm,
    int* __restrict__ idx_out, unsigned int* __restrict__ hist) {
  __shared__ f16 lAh[128 * 32];
  __shared__ f16 lAl[128 * 32];
  __shared__ f16 lBh[128 * 32];
  __shared__ f16 lBl[128 * 32];
  __shared__ float sxv[2][64];   // cross-wave publish: [wr][row-in-strip]
  __shared__ int   sxi[2][64];

  const int tid  = threadIdx.x;
  const int wid  = tid >> 6;
  const int lane = tid & 63;
  const int wr   = wid >> 1;        // wave row 0..1 (64-row strip)
  const int wc   = wid & 1;         // wave col 0..1 (64-col strip)
  const int lrow = lane & 15;       // frag row/col index
  const int lq   = lane >> 4;       // k-chunk 0..3
  const int rbase = blockIdx.x * 128;

  // staging lane mapping: 16 rows x 4 chunks of 16B per wave-issue
  const int srow = lane >> 2;
  const int scol = lane & 3;

  float minv[4][4];
  int   mini[4][4];
  #pragma unroll
  for (int m = 0; m < 4; ++m)
    #pragma unroll
    for (int r = 0; r < 4; ++r) { minv[m][r] = 3.4e38f; mini[m][r] = 0; }

  for (int vt = 0; vt < VCB; vt += 128) {
    f32x4 acc[4][4];
    #pragma unroll
    for (int m = 0; m < 4; ++m)
      #pragma unroll
      for (int n = 0; n < 4; ++n) {
        f32x4 zz = {0.f, 0.f, 0.f, 0.f};
        acc[m][n] = zz;
      }

    for (int kt = 0; kt < DIM; kt += 32) {
      __syncthreads();   // prior kt's ds_reads done before overwrite
      // stage 4 tiles [128][32] f16; wave wid covers chunks wid and wid+4.
      // XOR swizzle on within-row 16B chunk, applied on the GLOBAL source
      // (LDS stays linear per global_load_lds rules) and mirrored on reads.
      #pragma unroll
      for (int h = 0; h < 2; ++h) {
        int c    = wid + h * 4;
        int trow = c * 16 + srow;                    // tile row 0..127
        int sw   = (trow >> 1) & 3;
        int koff = kt + ((scol ^ sw) << 3);          // element offset in row
        size_t zoff = (size_t)(rbase + trow) * DIM + koff;
        size_t eoff = (size_t)(vt    + trow) * DIM + koff;
        async16(lAh + c * 512, zh + zoff);
        async16(lAl + c * 512, zl + zoff);
        async16(lBh + c * 512, eh + eoff);
        async16(lBl + c * 512, el + eoff);
      }
      __syncthreads();   // drains vmcnt -> tiles ready

      const int cchunk = lq ^ ((lrow >> 1) & 3);
      f16x8 ah[4], al[4];
      #pragma unroll
      for (int m = 0; m < 4; ++m) {
        int row = wr * 64 + m * 16 + lrow;
        int off = row * 64 + cchunk * 16;
        ah[m] = *(const f16x8*)((const char*)lAh + off);
        al[m] = *(const f16x8*)((const char*)lAl + off);
      }
      #pragma unroll
      for (int n = 0; n < 4; ++n) {
        int col = wc * 64 + n * 16 + lrow;
        int off = col * 64 + cchunk * 16;
        f16x8 bh = *(const f16x8*)((const char*)lBh + off);
        f16x8 bl = *(const f16x8*)((const char*)lBl + off);
        #pragma unroll
        for (int m = 0; m < 4; ++m) {
          acc[m][n] = __builtin_amdgcn_mfma_f32_16x16x32_f16(ah[m], bh, acc[m][n], 0, 0, 0);
          acc[m][n] = __builtin_amdgcn_mfma_f32_16x16x32_f16(ah[m], bl, acc[m][n], 0, 0, 0);
          acc[m][n] = __builtin_amdgcn_mfma_f32_16x16x32_f16(al[m], bh, acc[m][n], 0, 0, 0);
        }
      }
    }

    // epilogue: C/D layout col=lane&15, row=(lane>>4)*4+reg (m89/m91)
    #pragma unroll
    for (int n = 0; n < 4; ++n) {
      int j = vt + wc * 64 + n * 16 + lrow;
      float en = enorm[j];
      #pragma unroll
      for (int m = 0; m < 4; ++m)
        #pragma unroll
        for (int r = 0; r < 4; ++r) {
          float s = fmaf(-2.f, acc[m][n][r], en);
          if (s < minv[m][r]) { minv[m][r] = s; mini[m][r] = j; }
        }
    }
  }

  // reduce across the 16 lanes (lane bits 0..3) sharing each row; first-idx tie-break
  #pragma unroll
  for (int off = 1; off < 16; off <<= 1) {
    #pragma unroll
    for (int m = 0; m < 4; ++m)
      #pragma unroll
      for (int r = 0; r < 4; ++r) {
        float ov = __shfl_xor(minv[m][r], off);
        int   oi = __shfl_xor(mini[m][r], off);
        if (ov < minv[m][r] || (ov == minv[m][r] && oi < mini[m][r])) {
          minv[m][r] = ov; mini[m][r] = oi;
        }
      }
  }

  // cross-wave merge: wc==1 publishes, wc==0 merges and is sole writer.
  if (wc == 1 && lrow == 0) {
    #pragma unroll
    for (int m = 0; m < 4; ++m)
      #pragma unroll
      for (int r = 0; r < 4; ++r) {
        int li = m * 16 + lq * 4 + r;
        sxv[wr][li] = minv[m][r];
        sxi[wr][li] = mini[m][r];
      }
  }
  __syncthreads();
  if (wc == 0 && lrow == 0) {
    #pragma unroll
    for (int m = 0; m < 4; ++m)
      #pragma unroll
      for (int r = 0; r < 4; ++r) {
        int li = m * 16 + lq * 4 + r;
        float ov = sxv[wr][li];
        int   oi = sxi[wr][li];
        float v  = minv[m][r];
        int   bi = mini[m][r];
        if (ov < v || (ov == v && oi < bi)) { v = ov; bi = oi; }
        idx_out[rbase + wr * 64 + li] = bi;
        atomicAdd(&hist[bi], 1u);
      }
  }
}

// gather z_q = e[idx], write z_q_st + float indices, accumulate sum((z-z_q)^2)
__global__ __launch_bounds__(256) void gather_loss_kernel(
    const float* __restrict__ z, const float* __restrict__ e,
    const int* __restrict__ idx, float* __restrict__ zq_out,
    float* __restrict__ idxf_out, double* __restrict__ loss_part) {
  __shared__ float wsum[4];
  int tid  = threadIdx.x;
  int w    = tid >> 6;
  int lane = tid & 63;
  int n    = blockIdx.x * 4 + w;

  int ci = idx[n];
  const float4* zr = (const float4*)(z + (size_t)n  * DIM);
  const float4* er = (const float4*)(e + (size_t)ci * DIM);
  float4 zv = zr[lane];
  float4 ev = er[lane];
  ((float4*)(zq_out + (size_t)n * DIM))[lane] = ev;
  if (lane == 0) idxf_out[n] = (float)ci;

  float dx = zv.x - ev.x, dy = zv.y - ev.y, dz = zv.z - ev.z, dw = zv.w - ev.w;
  float s = dx*dx + dy*dy + dz*dz + dw*dw;
  #pragma unroll
  for (int off = 32; off; off >>= 1) s += __shfl_xor(s, off);
  if (lane == 0) wsum[w] = s;
  __syncthreads();
  if (tid == 0) {
    float bs = wsum[0] + wsum[1] + wsum[2] + wsum[3];
    atomicAdd(&loss_part[blockIdx.x & 255], (double)bs);
  }
}

__global__ __launch_bounds__(256) void finalize_kernel(
    const unsigned int* __restrict__ hist, const double* __restrict__ loss_part,
    float* __restrict__ out) {
  __shared__ double lsh[4];
  __shared__ float  hsh[4];
  __shared__ float  denom_sh;
  int tid = threadIdx.x, lane = tid & 63, w = tid >> 6;

  float hs = 0.f;
  for (int j = tid; j < VCB; j += 256) hs += (float)hist[j];
  double ls = loss_part[tid];
  #pragma unroll
  for (int off = 32; off; off >>= 1) {
    hs += __shfl_xor(hs, off);
    ls += __shfl_xor(ls, off);
  }
  if (lane == 0) { lsh[w] = ls; hsh[w] = hs; }
  __syncthreads();
  if (tid == 0) {
    double lt = lsh[0] + lsh[1] + lsh[2] + lsh[3];
    float  ht = hsh[0] + hsh[1] + hsh[2] + hsh[3];
    out[0] = (float)(lt / (double)((size_t)NROWS * DIM));
    denom_sh = ht + 1e-8f;
  }
  __syncthreads();
  float denom = denom_sh;
  float* prob = out + 1 + (size_t)NROWS * DIM + NROWS;
  for (int j = tid; j < VCB; j += 256) prob[j] = (float)hist[j] / denom;
}

extern "C" void kernel_launch(void* const* d_in, const int* in_sizes, int n_in,
                              void* d_out, int out_size, void* d_ws, size_t ws_size,
                              hipStream_t stream) {
  (void)in_sizes; (void)n_in; (void)out_size; (void)ws_size;
  const float* z = (const float*)d_in[0];
  const float* e = (const float*)d_in[1];
  float* out = (float*)d_out;
  char*  ws  = (char*)d_ws;

  int*          idx       = (int*)ws;
  unsigned int* hist      = (unsigned int*)(ws + 262144);
  double*       loss_part = (double*)(ws + 270336);
  float*        enorm     = (float*)(ws + 272384);
  f16*          e_hi      = (f16*)(ws + 524288);
  f16*          e_lo      = (f16*)(ws + 1572864);

  // z split lives in d_out's z_q region (scratch until gather pass).
  f16* z_hi = (f16*)(out + 4);
  f16* z_lo = z_hi + (size_t)NROWS * DIM;

  float* out_zq  = out + 1;
  float* out_idx = out + 1 + (size_t)NROWS * DIM;

  convert_kernel<<<1024, 256, 0, stream>>>(
      (const float4*)z, (short4*)z_hi, (short4*)z_lo, NROWS * DIM / 4);
  convert_kernel<<<128, 256, 0, stream>>>(
      (const float4*)e, (short4*)e_hi, (short4*)e_lo, VCB * DIM / 4);
  prep_kernel<<<512, 256, 0, stream>>>(e, enorm, hist, loss_part);
  argmin_kernel<<<NROWS / 128, 256, 0, stream>>>(
      z_hi, z_lo, e_hi, e_lo, enorm, idx, hist);
  gather_loss_kernel<<<NROWS / 4, 256, 0, stream>>>(
      z, e, idx, out_zq, out_idx, loss_part);
  finalize_kernel<<<1, 256, 0, stream>>>(hist, loss_part, out);
}

// Round 4
// 401.172 us; speedup vs baseline: 2.5628x; 1.0520x over previous
//
#include <hip/hip_runtime.h>

#define NROWS 65536   // B*T
#define DIM   256
#define VCB   2048

typedef _Float16 f16;
typedef _Float16 f16x8 __attribute__((ext_vector_type(8)));
typedef float    f32x4 __attribute__((ext_vector_type(4)));

// ---------------- ws layout (bytes) ----------------
// [0,        262144)  idx        int[NROWS]
// [262144,   270336)  hist       uint[VCB]
// [270336,   272384)  loss_part  double[256]
// [272384,   280576)  enorm      float[VCB]
// [524288,  1572864)  e_hi       f16[VCB*DIM]
// [1572864, 2621440)  e_lo       f16[VCB*DIM]
// z_hi/z_lo (64 MB) live in d_out's z_q region as scratch until the gather pass.

__device__ __forceinline__ void async16(void* lds, const void* g) {
  __builtin_amdgcn_global_load_lds(
      (const __attribute__((address_space(1))) void*)g,
      (__attribute__((address_space(3))) void*)lds, 16, 0, 0);
}

// fp32 -> (f16 hi, f16 lo) split, 4 elems/thread/iter, grid-stride
__global__ __launch_bounds__(256) void convert_kernel(
    const float4* __restrict__ src, short4* __restrict__ dhi,
    short4* __restrict__ dlo, int n4) {
  int stride = gridDim.x * 256;
  for (int i = blockIdx.x * 256 + threadIdx.x; i < n4; i += stride) {
    float4 v = src[i];
    union { f16 h[4]; short4 s; } H, L;
    H.h[0] = (f16)v.x; H.h[1] = (f16)v.y; H.h[2] = (f16)v.z; H.h[3] = (f16)v.w;
    L.h[0] = (f16)(v.x - (float)H.h[0]);
    L.h[1] = (f16)(v.y - (float)H.h[1]);
    L.h[2] = (f16)(v.z - (float)H.h[2]);
    L.h[3] = (f16)(v.w - (float)H.h[3]);
    dhi[i] = H.s; dlo[i] = L.s;
  }
}

// zero hist + loss partials, compute ||e_j||^2 (one wave per codebook row), fp32
__global__ __launch_bounds__(256) void prep_kernel(
    const float* __restrict__ e, float* __restrict__ enorm,
    unsigned int* __restrict__ hist, double* __restrict__ loss_part) {
  int tid = threadIdx.x;
  int gt = blockIdx.x * 256 + tid;
  if (gt < VCB) hist[gt] = 0u;
  if (gt < 256) loss_part[gt] = 0.0;
  int wid  = gt >> 6;
  int lane = tid & 63;
  if (wid < VCB) {
    const float4* row = (const float4*)(e + (size_t)wid * DIM);
    float4 v = row[lane];
    float s = v.x*v.x + v.y*v.y + v.z*v.z + v.w*v.w;
    #pragma unroll
    for (int off = 32; off; off >>= 1) s += __shfl_xor(s, off);
    if (lane == 0) enorm[wid] = s;
  }
}

// Fused split-f16 MFMA distance GEMM + row argmin, 2-phase double-buffered.
// 256 threads = 4 waves (2x2), tile 128 rows x 128 cols per vt step, BK=32.
// Per flattened step t: issue stage(t+1) into buf^1, ds_read+MFMA from buf,
// ONE __syncthreads() (vmcnt drain overlapped with the compute body).
__global__ __launch_bounds__(256) void argmin_kernel(
    const f16* __restrict__ zh, const f16* __restrict__ zl,
    const f16* __restrict__ eh, const f16* __restrict__ el,
    const float* __restrict__ enorm,
    int* __restrict__ idx_out, unsigned int* __restrict__ hist) {
  // [buf][tile]: tiles Ah(0), Al(1), Bh(2), Bl(3), each [128][32] f16 = 4096 f16
  __shared__ f16 lds[2][4 * 4096];
  __shared__ float sxv[2][64];   // cross-wave publish: [wr][row-in-strip]
  __shared__ int   sxi[2][64];

  const int tid  = threadIdx.x;
  const int wid  = tid >> 6;
  const int lane = tid & 63;
  const int wr   = wid >> 1;        // wave row 0..1 (64-row strip)
  const int wc   = wid & 1;         // wave col 0..1 (64-col strip)
  const int lrow = lane & 15;       // frag row/col index
  const int lq   = lane >> 4;       // k-chunk 0..3
  const int rbase = blockIdx.x * 128;

  // staging lane mapping: 16 rows x 4 chunks of 16B per wave-issue
  const int srow = lane >> 2;
  const int scol = lane & 3;

  // stage one (vt, kt) step's 4 tiles into buffer b.
  // XOR swizzle on within-row 16B chunk, applied on the GLOBAL source
  // (LDS stays linear per global_load_lds rules) and mirrored on reads.
  auto stage = [&](int b, int vt, int kt) {
    f16* base = lds[b];
    #pragma unroll
    for (int h = 0; h < 2; ++h) {
      int c    = wid + h * 4;
      int trow = c * 16 + srow;                    // tile row 0..127
      int sw   = (trow >> 1) & 3;
      int koff = kt + ((scol ^ sw) << 3);          // element offset in row
      size_t zoff = (size_t)(rbase + trow) * DIM + koff;
      size_t eoff = (size_t)(vt    + trow) * DIM + koff;
      async16(base +          c * 512, zh + zoff);
      async16(base +  4096 +  c * 512, zl + zoff);
      async16(base +  8192 +  c * 512, eh + eoff);
      async16(base + 12288 +  c * 512, el + eoff);
    }
  };

  float minv[4][4];
  int   mini[4][4];
  #pragma unroll
  for (int m = 0; m < 4; ++m)
    #pragma unroll
    for (int r = 0; r < 4; ++r) { minv[m][r] = 3.4e38f; mini[m][r] = 0; }

  int cur = 0;
  stage(0, 0, 0);
  __syncthreads();   // drains vmcnt(0): buf0 ready

  for (int vt = 0; vt < VCB; vt += 128) {
    f32x4 acc[4][4];
    #pragma unroll
    for (int m = 0; m < 4; ++m)
      #pragma unroll
      for (int n = 0; n < 4; ++n) {
        f32x4 zz = {0.f, 0.f, 0.f, 0.f};
        acc[m][n] = zz;
      }

    for (int ktep = 0; ktep < 8; ++ktep) {
      // prefetch next step into the other buffer (issue EARLY, drain at barrier)
      int t  = (vt >> 4) + ktep;       // flattened step = (vt/128)*8 + ktep
      int nt = t + 1;
      if (nt < (VCB / 128) * 8) {
        stage(cur ^ 1, (nt >> 3) << 7, (nt & 7) << 5);
      }

      const f16* lAh = lds[cur];
      const f16* lAl = lds[cur] + 4096;
      const f16* lBh = lds[cur] + 8192;
      const f16* lBl = lds[cur] + 12288;

      const int cchunk = lq ^ ((lrow >> 1) & 3);
      f16x8 ah[4], al[4];
      #pragma unroll
      for (int m = 0; m < 4; ++m) {
        int row = wr * 64 + m * 16 + lrow;
        int off = row * 64 + cchunk * 16;
        ah[m] = *(const f16x8*)((const char*)lAh + off);
        al[m] = *(const f16x8*)((const char*)lAl + off);
      }
      #pragma unroll
      for (int n = 0; n < 4; ++n) {
        int col = wc * 64 + n * 16 + lrow;
        int off = col * 64 + cchunk * 16;
        f16x8 bh = *(const f16x8*)((const char*)lBh + off);
        f16x8 bl = *(const f16x8*)((const char*)lBl + off);
        #pragma unroll
        for (int m = 0; m < 4; ++m) {
          acc[m][n] = __builtin_amdgcn_mfma_f32_16x16x32_f16(ah[m], bh, acc[m][n], 0, 0, 0);
          acc[m][n] = __builtin_amdgcn_mfma_f32_16x16x32_f16(ah[m], bl, acc[m][n], 0, 0, 0);
          acc[m][n] = __builtin_amdgcn_mfma_f32_16x16x32_f16(al[m], bh, acc[m][n], 0, 0, 0);
        }
      }
      __syncthreads();   // vmcnt(0)+lgkmcnt(0)+barrier: next buf ready, reads done
      cur ^= 1;
    }

    // epilogue: C/D layout col=lane&15, row=(lane>>4)*4+reg (m89/m91)
    #pragma unroll
    for (int n = 0; n < 4; ++n) {
      int j = vt + wc * 64 + n * 16 + lrow;
      float en = enorm[j];
      #pragma unroll
      for (int m = 0; m < 4; ++m)
        #pragma unroll
        for (int r = 0; r < 4; ++r) {
          float s = fmaf(-2.f, acc[m][n][r], en);
          if (s < minv[m][r]) { minv[m][r] = s; mini[m][r] = j; }
        }
    }
  }

  // reduce across the 16 lanes (lane bits 0..3) sharing each row; first-idx tie-break
  #pragma unroll
  for (int off = 1; off < 16; off <<= 1) {
    #pragma unroll
    for (int m = 0; m < 4; ++m)
      #pragma unroll
      for (int r = 0; r < 4; ++r) {
        float ov = __shfl_xor(minv[m][r], off);
        int   oi = __shfl_xor(mini[m][r], off);
        if (ov < minv[m][r] || (ov == minv[m][r] && oi < mini[m][r])) {
          minv[m][r] = ov; mini[m][r] = oi;
        }
      }
  }

  // cross-wave merge: wc==1 publishes, wc==0 merges and is sole writer.
  if (wc == 1 && lrow == 0) {
    #pragma unroll
    for (int m = 0; m < 4; ++m)
      #pragma unroll
      for (int r = 0; r < 4; ++r) {
        int li = m * 16 + lq * 4 + r;
        sxv[wr][li] = minv[m][r];
        sxi[wr][li] = mini[m][r];
      }
  }
  __syncthreads();
  if (wc == 0 && lrow == 0) {
    #pragma unroll
    for (int m = 0; m < 4; ++m)
      #pragma unroll
      for (int r = 0; r < 4; ++r) {
        int li = m * 16 + lq * 4 + r;
        float ov = sxv[wr][li];
        int   oi = sxi[wr][li];
        float v  = minv[m][r];
        int   bi = mini[m][r];
        if (ov < v || (ov == v && oi < bi)) { v = ov; bi = oi; }
        idx_out[rbase + wr * 64 + li] = bi;
        atomicAdd(&hist[bi], 1u);
      }
  }
}

// gather z_q = e[idx], write z_q_st + float indices, accumulate sum((z-z_q)^2)
__global__ __launch_bounds__(256) void gather_loss_kernel(
    const float* __restrict__ z, const float* __restrict__ e,
    const int* __restrict__ idx, float* __restrict__ zq_out,
    float* __restrict__ idxf_out, double* __restrict__ loss_part) {
  __shared__ float wsum[4];
  int tid  = threadIdx.x;
  int w    = tid >> 6;
  int lane = tid & 63;
  int n    = blockIdx.x * 4 + w;

  int ci = idx[n];
  const float4* zr = (const float4*)(z + (size_t)n  * DIM);
  const float4* er = (const float4*)(e + (size_t)ci * DIM);
  float4 zv = zr[lane];
  float4 ev = er[lane];
  ((float4*)(zq_out + (size_t)n * DIM))[lane] = ev;
  if (lane == 0) idxf_out[n] = (float)ci;

  float dx = zv.x - ev.x, dy = zv.y - ev.y, dz = zv.z - ev.z, dw = zv.w - ev.w;
  float s = dx*dx + dy*dy + dz*dz + dw*dw;
  #pragma unroll
  for (int off = 32; off; off >>= 1) s += __shfl_xor(s, off);
  if (lane == 0) wsum[w] = s;
  __syncthreads();
  if (tid == 0) {
    float bs = wsum[0] + wsum[1] + wsum[2] + wsum[3];
    atomicAdd(&loss_part[blockIdx.x & 255], (double)bs);
  }
}

__global__ __launch_bounds__(256) void finalize_kernel(
    const unsigned int* __restrict__ hist, const double* __restrict__ loss_part,
    float* __restrict__ out) {
  __shared__ double lsh[4];
  __shared__ float  hsh[4];
  __shared__ float  denom_sh;
  int tid = threadIdx.x, lane = tid & 63, w = tid >> 6;

  float hs = 0.f;
  for (int j = tid; j < VCB; j += 256) hs += (float)hist[j];
  double ls = loss_part[tid];
  #pragma unroll
  for (int off = 32; off; off >>= 1) {
    hs += __shfl_xor(hs, off);
    ls += __shfl_xor(ls, off);
  }
  if (lane == 0) { lsh[w] = ls; hsh[w] = hs; }
  __syncthreads();
  if (tid == 0) {
    double lt = lsh[0] + lsh[1] + lsh[2] + lsh[3];
    float  ht = hsh[0] + hsh[1] + hsh[2] + hsh[3];
    out[0] = (float)(lt / (double)((size_t)NROWS * DIM));
    denom_sh = ht + 1e-8f;
  }
  __syncthreads();
  float denom = denom_sh;
  float* prob = out + 1 + (size_t)NROWS * DIM + NROWS;
  for (int j = tid; j < VCB; j += 256) prob[j] = (float)hist[j] / denom;
}

extern "C" void kernel_launch(void* const* d_in, const int* in_sizes, int n_in,
                              void* d_out, int out_size, void* d_ws, size_t ws_size,
                              hipStream_t stream) {
  (void)in_sizes; (void)n_in; (void)out_size; (void)ws_size;
  const float* z = (const float*)d_in[0];
  const float* e = (const float*)d_in[1];
  float* out = (float*)d_out;
  char*  ws  = (char*)d_ws;

  int*          idx       = (int*)ws;
  unsigned int* hist      = (unsigned int*)(ws + 262144);
  double*       loss_part = (double*)(ws + 270336);
  float*        enorm     = (float*)(ws + 272384);
  f16*          e_hi      = (f16*)(ws + 524288);
  f16*          e_lo      = (f16*)(ws + 1572864);

  // z split lives in d_out's z_q region (scratch until gather pass).
  f16* z_hi = (f16*)(out + 4);
  f16* z_lo = z_hi + (size_t)NROWS * DIM;

  float* out_zq  = out + 1;
  float* out_idx = out + 1 + (size_t)NROWS * DIM;

  convert_kernel<<<1024, 256, 0, stream>>>(
      (const float4*)z, (short4*)z_hi, (short4*)z_lo, NROWS * DIM / 4);
  convert_kernel<<<128, 256, 0, stream>>>(
      (const float4*)e, (short4*)e_hi, (short4*)e_lo, VCB * DIM / 4);
  prep_kernel<<<512, 256, 0, stream>>>(e, enorm, hist, loss_part);
  argmin_kernel<<<NROWS / 128, 256, 0, stream>>>(
      z_hi, z_lo, e_hi, e_lo, enorm, idx, hist);
  gather_loss_kernel<<<NROWS / 4, 256, 0, stream>>>(
      z, e, idx, out_zq, out_idx, loss_part);
  finalize_kernel<<<1, 256, 0, stream>>>(hist, loss_part, out);
}

// Round 5
// 316.731 us; speedup vs baseline: 3.2460x; 1.2666x over previous
//
#include <hip/hip_runtime.h>

#define NROWS 65536   // B*T
#define DIM   256
#define VCB   2048

typedef _Float16 f16;
typedef _Float16 f16x8 __attribute__((ext_vector_type(8)));
typedef float    f32x4 __attribute__((ext_vector_type(4)));

// ---------------- ws layout (bytes) ----------------
// [0,        262144)  idx        int[NROWS]
// [262144,   270336)  hist       uint[VCB]
// [270336,   272384)  loss_part  double[256]
// [272384,   280576)  enorm      float[VCB]
// [524288,  1572864)  e_hi       f16[VCB*DIM]
// [1572864, 2621440)  e_lo       f16[VCB*DIM]
// z_hi/z_lo (64 MB) live in d_out's z_q region as scratch until the gather pass.

__device__ __forceinline__ void async16(void* lds, const void* g) {
  __builtin_amdgcn_global_load_lds(
      (const __attribute__((address_space(1))) void*)g,
      (__attribute__((address_space(3))) void*)lds, 16, 0, 0);
}

// fp32 -> (f16 hi, f16 lo) split, 4 elems/thread/iter, grid-stride
__global__ __launch_bounds__(256) void convert_kernel(
    const float4* __restrict__ src, short4* __restrict__ dhi,
    short4* __restrict__ dlo, int n4) {
  int stride = gridDim.x * 256;
  for (int i = blockIdx.x * 256 + threadIdx.x; i < n4; i += stride) {
    float4 v = src[i];
    union { f16 h[4]; short4 s; } H, L;
    H.h[0] = (f16)v.x; H.h[1] = (f16)v.y; H.h[2] = (f16)v.z; H.h[3] = (f16)v.w;
    L.h[0] = (f16)(v.x - (float)H.h[0]);
    L.h[1] = (f16)(v.y - (float)H.h[1]);
    L.h[2] = (f16)(v.z - (float)H.h[2]);
    L.h[3] = (f16)(v.w - (float)H.h[3]);
    dhi[i] = H.s; dlo[i] = L.s;
  }
}

// zero hist + loss partials, compute ||e_j||^2 (one wave per codebook row), fp32
__global__ __launch_bounds__(256) void prep_kernel(
    const float* __restrict__ e, float* __restrict__ enorm,
    unsigned int* __restrict__ hist, double* __restrict__ loss_part) {
  int tid = threadIdx.x;
  int gt = blockIdx.x * 256 + tid;
  if (gt < VCB) hist[gt] = 0u;
  if (gt < 256) loss_part[gt] = 0.0;
  int wid  = gt >> 6;
  int lane = tid & 63;
  if (wid < VCB) {
    const float4* row = (const float4*)(e + (size_t)wid * DIM);
    float4 v = row[lane];
    float s = v.x*v.x + v.y*v.y + v.z*v.z + v.w*v.w;
    #pragma unroll
    for (int off = 32; off; off >>= 1) s += __shfl_xor(s, off);
    if (lane == 0) enorm[wid] = s;
  }
}

// Fused split-f16 MFMA distance GEMM + row argmin, 2-buffer pipeline with
// COUNTED vmcnt (T4): per step issue stage(t+1) (8 loads/thread), then
// s_waitcnt vmcnt(8) + s_barrier (prev step's loads landed, block-wide),
// compute, s_barrier (WAR). Loads stay in flight across the whole body.
__global__ __launch_bounds__(256) void argmin_kernel(
    const f16* __restrict__ zh, const f16* __restrict__ zl,
    const f16* __restrict__ eh, const f16* __restrict__ el,
    const float* __restrict__ enorm,
    int* __restrict__ idx_out, unsigned int* __restrict__ hist) {
  // [buf][tile]: tiles Ah(0), Al(1), Bh(2), Bl(3), each [128][32] f16 = 4096 f16
  __shared__ f16 lds[2][4 * 4096];
  __shared__ float sxv[2][64];   // cross-wave publish: [wr][row-in-strip]
  __shared__ int   sxi[2][64];

  const int tid  = threadIdx.x;
  const int wid  = tid >> 6;
  const int lane = tid & 63;
  const int wr   = wid >> 1;        // wave row 0..1 (64-row strip)
  const int wc   = wid & 1;         // wave col 0..1 (64-col strip)
  const int lrow = lane & 15;       // frag row/col index
  const int lq   = lane >> 4;       // k-chunk 0..3
  const int rbase = blockIdx.x * 128;

  // staging lane mapping: 16 rows x 4 chunks of 16B per wave-issue
  const int srow = lane >> 2;
  const int scol = lane & 3;

  // stage one (vt, kt) step's 4 tiles into buffer b: 8 global_load_lds/thread.
  // XOR swizzle on within-row 16B chunk, applied on the GLOBAL source
  // (LDS stays linear per global_load_lds rules) and mirrored on reads.
  auto stage = [&](int b, int vt, int kt) {
    f16* base = lds[b];
    #pragma unroll
    for (int h = 0; h < 2; ++h) {
      int c    = wid + h * 4;
      int trow = c * 16 + srow;                    // tile row 0..127
      int sw   = (trow >> 1) & 3;
      int koff = kt + ((scol ^ sw) << 3);          // element offset in row
      size_t zoff = (size_t)(rbase + trow) * DIM + koff;
      size_t eoff = (size_t)(vt    + trow) * DIM + koff;
      async16(base +          c * 512, zh + zoff);
      async16(base +  4096 +  c * 512, zl + zoff);
      async16(base +  8192 +  c * 512, eh + eoff);
      async16(base + 12288 +  c * 512, el + eoff);
    }
  };

  float minv[4][4];
  int   mini[4][4];
  #pragma unroll
  for (int m = 0; m < 4; ++m)
    #pragma unroll
    for (int r = 0; r < 4; ++r) { minv[m][r] = 3.4e38f; mini[m][r] = 0; }

  const int NSTEP = (VCB / 128) * 8;   // 128 flattened (vt,kt) steps
  int cur = 0;
  stage(0, 0, 0);

  for (int vt = 0; vt < VCB; vt += 128) {
    f32x4 acc[4][4];
    #pragma unroll
    for (int m = 0; m < 4; ++m)
      #pragma unroll
      for (int n = 0; n < 4; ++n) {
        f32x4 zz = {0.f, 0.f, 0.f, 0.f};
        acc[m][n] = zz;
      }

    for (int ktep = 0; ktep < 8; ++ktep) {
      // prefetch next step into the other buffer; clamp keeps vmcnt uniform
      int nt = (vt >> 4) + ktep + 1;
      if (nt >= NSTEP) nt = 0;           // harmless re-stage of step 0 at the end
      stage(cur ^ 1, (nt >> 3) << 7, (nt & 7) << 5);

      // counted wait: only the 8 loads of the PREVIOUS step must have landed
      asm volatile("s_waitcnt vmcnt(8)" ::: "memory");
      asm volatile("s_barrier" ::: "memory");
      __builtin_amdgcn_sched_barrier(0);

      const f16* lAh = lds[cur];
      const f16* lAl = lds[cur] + 4096;
      const f16* lBh = lds[cur] + 8192;
      const f16* lBl = lds[cur] + 12288;

      const int cchunk = lq ^ ((lrow >> 1) & 3);
      f16x8 ah[4], al[4];
      #pragma unroll
      for (int m = 0; m < 4; ++m) {
        int row = wr * 64 + m * 16 + lrow;
        int off = row * 64 + cchunk * 16;
        ah[m] = *(const f16x8*)((const char*)lAh + off);
        al[m] = *(const f16x8*)((const char*)lAl + off);
      }
      #pragma unroll
      for (int n = 0; n < 4; ++n) {
        int col = wc * 64 + n * 16 + lrow;
        int off = col * 64 + cchunk * 16;
        f16x8 bh = *(const f16x8*)((const char*)lBh + off);
        f16x8 bl = *(const f16x8*)((const char*)lBl + off);
        #pragma unroll
        for (int m = 0; m < 4; ++m) {
          acc[m][n] = __builtin_amdgcn_mfma_f32_16x16x32_f16(ah[m], bh, acc[m][n], 0, 0, 0);
          acc[m][n] = __builtin_amdgcn_mfma_f32_16x16x32_f16(ah[m], bl, acc[m][n], 0, 0, 0);
          acc[m][n] = __builtin_amdgcn_mfma_f32_16x16x32_f16(al[m], bh, acc[m][n], 0, 0, 0);
        }
      }

      // WAR: all waves' LDS reads complete (consumed by MFMAs) before the
      // next step's stage overwrites buf[cur].
      __builtin_amdgcn_sched_barrier(0);
      asm volatile("s_barrier" ::: "memory");
      cur ^= 1;
    }

    // epilogue: C/D layout col=lane&15, row=(lane>>4)*4+reg (m89/m91)
    #pragma unroll
    for (int n = 0; n < 4; ++n) {
      int j = vt + wc * 64 + n * 16 + lrow;
      float en = enorm[j];
      #pragma unroll
      for (int m = 0; m < 4; ++m)
        #pragma unroll
        for (int r = 0; r < 4; ++r) {
          float s = fmaf(-2.f, acc[m][n][r], en);
          if (s < minv[m][r]) { minv[m][r] = s; mini[m][r] = j; }
        }
    }
  }

  // reduce across the 16 lanes (lane bits 0..3) sharing each row; first-idx tie-break
  #pragma unroll
  for (int off = 1; off < 16; off <<= 1) {
    #pragma unroll
    for (int m = 0; m < 4; ++m)
      #pragma unroll
      for (int r = 0; r < 4; ++r) {
        float ov = __shfl_xor(minv[m][r], off);
        int   oi = __shfl_xor(mini[m][r], off);
        if (ov < minv[m][r] || (ov == minv[m][r] && oi < mini[m][r])) {
          minv[m][r] = ov; mini[m][r] = oi;
        }
      }
  }

  // cross-wave merge: wc==1 publishes, wc==0 merges and is sole writer.
  if (wc == 1 && lrow == 0) {
    #pragma unroll
    for (int m = 0; m < 4; ++m)
      #pragma unroll
      for (int r = 0; r < 4; ++r) {
        int li = m * 16 + lq * 4 + r;
        sxv[wr][li] = minv[m][r];
        sxi[wr][li] = mini[m][r];
      }
  }
  __syncthreads();
  if (wc == 0 && lrow == 0) {
    #pragma unroll
    for (int m = 0; m < 4; ++m)
      #pragma unroll
      for (int r = 0; r < 4; ++r) {
        int li = m * 16 + lq * 4 + r;
        float ov = sxv[wr][li];
        int   oi = sxi[wr][li];
        float v  = minv[m][r];
        int   bi = mini[m][r];
        if (ov < v || (ov == v && oi < bi)) { v = ov; bi = oi; }
        idx_out[rbase + wr * 64 + li] = bi;
        atomicAdd(&hist[bi], 1u);
      }
  }
}

// gather z_q = e[idx], write z_q_st + float indices, accumulate sum((z-z_q)^2)
__global__ __launch_bounds__(256) void gather_loss_kernel(
    const float* __restrict__ z, const float* __restrict__ e,
    const int* __restrict__ idx, float* __restrict__ zq_out,
    float* __restrict__ idxf_out, double* __restrict__ loss_part) {
  __shared__ float wsum[4];
  int tid  = threadIdx.x;
  int w    = tid >> 6;
  int lane = tid & 63;
  int n    = blockIdx.x * 4 + w;

  int ci = idx[n];
  const float4* zr = (const float4*)(z + (size_t)n  * DIM);
  const float4* er = (const float4*)(e + (size_t)ci * DIM);
  float4 zv = zr[lane];
  float4 ev = er[lane];
  ((float4*)(zq_out + (size_t)n * DIM))[lane] = ev;
  if (lane == 0) idxf_out[n] = (float)ci;

  float dx = zv.x - ev.x, dy = zv.y - ev.y, dz = zv.z - ev.z, dw = zv.w - ev.w;
  float s = dx*dx + dy*dy + dz*dz + dw*dw;
  #pragma unroll
  for (int off = 32; off; off >>= 1) s += __shfl_xor(s, off);
  if (lane == 0) wsum[w] = s;
  __syncthreads();
  if (tid == 0) {
    float bs = wsum[0] + wsum[1] + wsum[2] + wsum[3];
    atomicAdd(&loss_part[blockIdx.x & 255], (double)bs);
  }
}

__global__ __launch_bounds__(256) void finalize_kernel(
    const unsigned int* __restrict__ hist, const double* __restrict__ loss_part,
    float* __restrict__ out) {
  __shared__ double lsh[4];
  __shared__ float  hsh[4];
  __shared__ float  denom_sh;
  int tid = threadIdx.x, lane = tid & 63, w = tid >> 6;

  float hs = 0.f;
  for (int j = tid; j < VCB; j += 256) hs += (float)hist[j];
  double ls = loss_part[tid];
  #pragma unroll
  for (int off = 32; off; off >>= 1) {
    hs += __shfl_xor(hs, off);
    ls += __shfl_xor(ls, off);
  }
  if (lane == 0) { lsh[w] = ls; hsh[w] = hs; }
  __syncthreads();
  if (tid == 0) {
    double lt = lsh[0] + lsh[1] + lsh[2] + lsh[3];
    float  ht = hsh[0] + hsh[1] + hsh[2] + hsh[3];
    out[0] = (float)(lt / (double)((size_t)NROWS * DIM));
    denom_sh = ht + 1e-8f;
  }
  __syncthreads();
  float denom = denom_sh;
  float* prob = out + 1 + (size_t)NROWS * DIM + NROWS;
  for (int j = tid; j < VCB; j += 256) prob[j] = (float)hist[j] / denom;
}

extern "C" void kernel_launch(void* const* d_in, const int* in_sizes, int n_in,
                              void* d_out, int out_size, void* d_ws, size_t ws_size,
                              hipStream_t stream) {
  (void)in_sizes; (void)n_in; (void)out_size; (void)ws_size;
  const float* z = (const float*)d_in[0];
  const float* e = (const float*)d_in[1];
  float* out = (float*)d_out;
  char*  ws  = (char*)d_ws;

  int*          idx       = (int*)ws;
  unsigned int* hist      = (unsigned int*)(ws + 262144);
  double*       loss_part = (double*)(ws + 270336);
  float*        enorm     = (float*)(ws + 272384);
  f16*          e_hi      = (f16*)(ws + 524288);
  f16*          e_lo      = (f16*)(ws + 1572864);

  // z split lives in d_out's z_q region (scratch until gather pass).
  f16* z_hi = (f16*)(out + 4);
  f16* z_lo = z_hi + (size_t)NROWS * DIM;

  float* out_zq  = out + 1;
  float* out_idx = out + 1 + (size_t)NROWS * DIM;

  convert_kernel<<<1024, 256, 0, stream>>>(
      (const float4*)z, (short4*)z_hi, (short4*)z_lo, NROWS * DIM / 4);
  convert_kernel<<<128, 256, 0, stream>>>(
      (const float4*)e, (short4*)e_hi, (short4*)e_lo, VCB * DIM / 4);
  prep_kernel<<<512, 256, 0, stream>>>(e, enorm, hist, loss_part);
  argmin_kernel<<<NROWS / 128, 256, 0, stream>>>(
      z_hi, z_lo, e_hi, e_lo, enorm, idx, hist);
  gather_loss_kernel<<<NROWS / 4, 256, 0, stream>>>(
      z, e, idx, out_zq, out_idx, loss_part);
  finalize_kernel<<<1, 256, 0, stream>>>(hist, loss_part, out);
}